// Round 1
// baseline (18319.577 us; speedup 1.0000x reference)
//
#include <hip/hip_runtime.h>
#include <hip/hip_bf16.h>
#include <math.h>

#define BN_ROWS 16384   // B*N
#define DIM 512
#define HEADS 8
#define DK 64
#define FF 2048
#define LAYERS 4
#define NSEQ 512
#define BATCH 32

// ---------------- embed: h = x @ We + be ----------------
__global__ __launch_bounds__(512)
void embed_kernel(const float* __restrict__ x, const float* __restrict__ We,
                  const float* __restrict__ be, float* __restrict__ h) {
    int row = blockIdx.x;         // 0..16383
    int d = threadIdx.x;          // 0..511
    const float* xr = x + (long)row * 8;
    float acc = be[d];
#pragma unroll
    for (int c = 0; c < 8; c++) acc += xr[c] * We[c * DIM + d];
    h[(long)row * DIM + d] = acc;
}

// ---------------- generic f32 GEMM: C = A@B (+bias)(+relu) ----------------
// 64x64 tile, 256 threads, 4x4 per thread, K-step 16.
// blockIdx.z selects a sub-problem: B += z*strideB, C += z*strideCcol (column offset).
template<int RELU, int BIAS>
__global__ __launch_bounds__(256)
void gemm_f32(const float* __restrict__ A, const float* __restrict__ Bm,
              const float* __restrict__ bias, float* __restrict__ C,
              int M, int N, int K, int lda, int ldb, int ldc,
              long strideB, long strideCcol) {
    const int zb = blockIdx.z;
    const float* Bz = Bm + (long)zb * strideB;
    float* Cz = C + zb * strideCcol;
    const int row0 = blockIdx.y * 64, col0 = blockIdx.x * 64;
    __shared__ float As[16][65];   // As[kk][r], padded vs bank conflict
    __shared__ float Bs[16][64];   // Bs[kk][c]
    const int tid = threadIdx.x;
    const int tx = tid & 15, ty = tid >> 4;
    float acc[4][4] = {};
    for (int k0 = 0; k0 < K; k0 += 16) {
#pragma unroll
        for (int rep = 0; rep < 4; rep++) {
            int e = tid + rep * 256;
            int r = e >> 4, kk = e & 15;
            As[kk][r] = A[(long)(row0 + r) * lda + k0 + kk];
        }
#pragma unroll
        for (int rep = 0; rep < 4; rep++) {
            int e = tid + rep * 256;
            int kk = e >> 6, c = e & 63;
            Bs[kk][c] = Bz[(long)(k0 + kk) * ldb + col0 + c];
        }
        __syncthreads();
#pragma unroll
        for (int kk = 0; kk < 16; kk++) {
            float a[4], b[4];
#pragma unroll
            for (int i = 0; i < 4; i++) a[i] = As[kk][ty * 4 + i];
#pragma unroll
            for (int j = 0; j < 4; j++) b[j] = Bs[kk][tx * 4 + j];
#pragma unroll
            for (int i = 0; i < 4; i++)
#pragma unroll
                for (int j = 0; j < 4; j++)
                    acc[i][j] += a[i] * b[j];
        }
        __syncthreads();
    }
#pragma unroll
    for (int i = 0; i < 4; i++) {
        int r = row0 + ty * 4 + i;
#pragma unroll
        for (int j = 0; j < 4; j++) {
            int c = col0 + tx * 4 + j;
            float v = acc[i][j];
            if (BIAS) v += bias[c];
            if (RELU) v = fmaxf(v, 0.f);
            Cz[(long)r * ldc + c] = v;
        }
    }
}

// ---------------- attention: per (qtile16, b, head) block ----------------
// Q,K,V: [BN][512] row-major, head hd at col hd*64. att out same layout.
__global__ __launch_bounds__(256)
void attn_kernel(const float* __restrict__ Q, const float* __restrict__ K,
                 const float* __restrict__ V, const int* __restrict__ mask,
                 float* __restrict__ att) {
    const int b = blockIdx.y, hd = blockIdx.z, q0 = blockIdx.x * 16;
    __shared__ float S[16][NSEQ];
    __shared__ float Qs[16][DK];
    __shared__ float red[16][16];
    const int tid = threadIdx.x;
    const long base = ((long)b * NSEQ) * DIM + hd * DK;

    for (int e = tid; e < 16 * DK; e += 256) {
        int r = e >> 6, c = e & 63;
        Qs[r][c] = Q[base + (long)(q0 + r) * DIM + c];
    }
    __syncthreads();

    const int r = tid >> 4, g = tid & 15;
    const int* mrow = mask + ((long)b * NSEQ + q0 + r) * NSEQ;
    const float4* Q4r = (const float4*)Qs[r];

    // phase 1: scores for n in [g*32, g*32+32)
    for (int n = g * 32; n < g * 32 + 32; n++) {
        const float4* K4 = (const float4*)(K + base + (long)n * DIM);
        float acc = 0.f;
#pragma unroll
        for (int c4 = 0; c4 < 16; c4++) {
            float4 kv = K4[c4], qv = Q4r[c4];
            acc += qv.x * kv.x + qv.y * kv.y + qv.z * kv.z + qv.w * kv.w;
        }
        S[r][n] = mrow[n] ? -INFINITY : acc * 0.125f;
    }
    __syncthreads();

    // phase 2: softmax over row r, 16 threads cooperate
    float m = -INFINITY;
    for (int n = g; n < NSEQ; n += 16) m = fmaxf(m, S[r][n]);
    red[r][g] = m;
    __syncthreads();
    m = red[r][0];
#pragma unroll
    for (int j = 1; j < 16; j++) m = fmaxf(m, red[r][j]);
    float sum = 0.f;
    for (int n = g; n < NSEQ; n += 16) {
        float p = expf(S[r][n] - m);   // exp(-inf - m) = 0 for masked
        S[r][n] = p;
        sum += p;
    }
    __syncthreads();
    red[r][g] = sum;
    __syncthreads();
    float tot = red[r][0];
#pragma unroll
    for (int j = 1; j < 16; j++) tot += red[r][j];
    float inv = 1.f / tot;
    for (int n = g; n < NSEQ; n += 16) S[r][n] *= inv;
    __syncthreads();

    // phase 3: out[r][g*4 .. g*4+4) = sum_n P[r][n] * V[n][k]
    float4 acc = {0.f, 0.f, 0.f, 0.f};
    for (int n = 0; n < NSEQ; n++) {
        float p = S[r][n];
        float4 vv = *(const float4*)(V + base + (long)n * DIM + g * 4);
        acc.x += p * vv.x; acc.y += p * vv.y; acc.z += p * vv.z; acc.w += p * vv.w;
    }
    *(float4*)(att + ((long)b * NSEQ + q0 + r) * DIM + hd * DK + g * 4) = acc;
}

// ---------------- BN stats: s = a + b, accumulate per-channel sum/sumsq ----------------
__global__ __launch_bounds__(512)
void bn_stats(const float* __restrict__ a, const float* __restrict__ bb,
              float* __restrict__ s, float* __restrict__ sums) {
    const int c = threadIdx.x;
    float ps = 0.f, pq = 0.f;
    for (int r = blockIdx.x; r < BN_ROWS; r += gridDim.x) {
        long idx = (long)r * DIM + c;
        float v = a[idx] + bb[idx];
        s[idx] = v;
        ps += v;
        pq += v * v;
    }
    atomicAdd(&sums[c], ps);
    atomicAdd(&sums[DIM + c], pq);
}

__global__ __launch_bounds__(256)
void bn_apply(const float* __restrict__ s, const float* __restrict__ sums,
              const float* __restrict__ g, const float* __restrict__ bt,
              float* __restrict__ h) {
    long idx = (long)blockIdx.x * 256 + threadIdx.x;
    int c = idx & (DIM - 1);
    float mu = sums[c] * (1.f / BN_ROWS);
    float var = sums[DIM + c] * (1.f / BN_ROWS) - mu * mu;
    h[idx] = (s[idx] - mu) * rsqrtf(var + 1e-5f) * g[c] + bt[c];
}

// ---------------- final outputs ----------------
__global__ __launch_bounds__(256)
void copy_kernel(const float* __restrict__ src, float* __restrict__ dst) {
    long idx = (long)blockIdx.x * 256 + threadIdx.x;
    dst[idx] = src[idx];
}

__global__ __launch_bounds__(512)
void mean_kernel(const float* __restrict__ h, float* __restrict__ out) {
    int b = blockIdx.x, d = threadIdx.x;
    float acc = 0.f;
    for (int n = 0; n < NSEQ; n++) acc += h[((long)b * NSEQ + n) * DIM + d];
    out[(long)b * DIM + d] = acc * (1.f / NSEQ);
}

extern "C" void kernel_launch(void* const* d_in, const int* in_sizes, int n_in,
                              void* d_out, int out_size, void* d_ws, size_t ws_size,
                              hipStream_t stream) {
    const float* x   = (const float*)d_in[0];
    const int*   mask= (const int*)d_in[1];
    const float* We  = (const float*)d_in[2];
    const float* be  = (const float*)d_in[3];
    const float* Wq  = (const float*)d_in[4];
    const float* Wk  = (const float*)d_in[5];
    const float* Wv  = (const float*)d_in[6];
    const float* Wo  = (const float*)d_in[7];
    const float* g1  = (const float*)d_in[8];
    const float* bt1 = (const float*)d_in[9];
    const float* g2  = (const float*)d_in[10];
    const float* bt2 = (const float*)d_in[11];
    const float* W1  = (const float*)d_in[12];
    const float* bf1 = (const float*)d_in[13];
    const float* W2  = (const float*)d_in[14];
    const float* bf2 = (const float*)d_in[15];
    float* out = (float*)d_out;
    float* ws  = (float*)d_ws;

    const size_t M1 = (size_t)BN_ROWS * DIM;   // 8388608
    float* h    = ws;
    float* sbuf = ws + M1;
    float* Qb   = ws + 2 * M1;
    float* Kb   = ws + 3 * M1;
    float* Vb   = ws + 4 * M1;
    float* attb = ws + 5 * M1;
    float* stats= ws + 6 * M1;   // 1024 floats
    float* ffh  = Qb;            // reuse (4096*2048 == M1)

    embed_kernel<<<dim3(BN_ROWS), dim3(512), 0, stream>>>(x, We, be, h);

    for (int l = 0; l < LAYERS; l++) {
        const long wqk_off = (long)l * HEADS * DIM * DK;
        // QKV projections: per-head GEMM via grid.z
        gemm_f32<0,0><<<dim3(1, 256, 8), dim3(256), 0, stream>>>(
            h, Wq + wqk_off, nullptr, Qb, BN_ROWS, DK, DIM, DIM, DK, DIM,
            (long)DIM * DK, (long)DK);
        gemm_f32<0,0><<<dim3(1, 256, 8), dim3(256), 0, stream>>>(
            h, Wk + wqk_off, nullptr, Kb, BN_ROWS, DK, DIM, DIM, DK, DIM,
            (long)DIM * DK, (long)DK);
        gemm_f32<0,0><<<dim3(1, 256, 8), dim3(256), 0, stream>>>(
            h, Wv + wqk_off, nullptr, Vb, BN_ROWS, DK, DIM, DIM, DK, DIM,
            (long)DIM * DK, (long)DK);

        attn_kernel<<<dim3(NSEQ / 16, BATCH, HEADS), dim3(256), 0, stream>>>(
            Qb, Kb, Vb, mask, attb);

        // out-proj: att[BN,512] @ Wo[l] (512x512) -> Qb (reused)
        gemm_f32<0,0><<<dim3(8, 256, 1), dim3(256), 0, stream>>>(
            attb, Wo + (long)l * HEADS * DK * DIM, nullptr, Qb,
            BN_ROWS, DIM, DIM, DIM, DIM, DIM, 0, 0);

        hipMemsetAsync(stats, 0, 1024 * sizeof(float), stream);
        bn_stats<<<dim3(128), dim3(512), 0, stream>>>(h, Qb, sbuf, stats);
        bn_apply<<<dim3(M1 / 256), dim3(256), 0, stream>>>(
            sbuf, stats, g1 + l * DIM, bt1 + l * DIM, h);

        // FFN, chunked over rows (4 chunks of 4096)
        for (int c = 0; c < 4; c++) {
            long r0 = (long)c * 4096;
            gemm_f32<1,1><<<dim3(FF / 64, 4096 / 64, 1), dim3(256), 0, stream>>>(
                h + r0 * DIM, W1 + (long)l * DIM * FF, bf1 + (long)l * FF, ffh,
                4096, FF, DIM, DIM, FF, FF, 0, 0);
            gemm_f32<0,1><<<dim3(DIM / 64, 4096 / 64, 1), dim3(256), 0, stream>>>(
                ffh, W2 + (long)l * FF * DIM, bf2 + (long)l * DIM, attb + r0 * DIM,
                4096, DIM, FF, FF, DIM, DIM, 0, 0);
        }

        hipMemsetAsync(stats, 0, 1024 * sizeof(float), stream);
        bn_stats<<<dim3(128), dim3(512), 0, stream>>>(h, attb, sbuf, stats);
        bn_apply<<<dim3(M1 / 256), dim3(256), 0, stream>>>(
            sbuf, stats, g2 + l * DIM, bt2 + l * DIM, h);
    }

    copy_kernel<<<dim3(M1 / 256), dim3(256), 0, stream>>>(h, out);
    mean_kernel<<<dim3(BATCH), dim3(512), 0, stream>>>(h, out + M1);
}

// Round 3
// 3666.642 us; speedup vs baseline: 4.9963x; 4.9963x over previous
//
#include <hip/hip_runtime.h>
#include <hip/hip_bf16.h>
#include <math.h>

#define BN_ROWS 16384   // B*N
#define DIM 512
#define FF 2048
#define LAYERS 4
#define NSEQ 512
#define BATCH 32

typedef __attribute__((ext_vector_type(8))) short short8;
typedef __attribute__((ext_vector_type(4))) short short4v;
typedef __attribute__((ext_vector_type(4))) float f32x4;
typedef __hip_bfloat16 bf16;

__device__ __forceinline__ short f2b(float x) {
    bf16 b = __float2bfloat16(x);
    return *reinterpret_cast<short*>(&b);
}
__device__ __forceinline__ void split2(float v, bf16& hi, bf16& lo) {
    hi = __float2bfloat16(v);
    lo = __float2bfloat16(v - __bfloat162float(hi));
}
__device__ __forceinline__ f32x4 mfma_bf16(short8 a, short8 b, f32x4 c) {
    return __builtin_amdgcn_mfma_f32_16x16x32_bf16(a, b, c, 0, 0, 0);
}
__device__ __forceinline__ void gload_lds16(const bf16* g, bf16* l) {
    __builtin_amdgcn_global_load_lds(
        (const __attribute__((address_space(1))) unsigned int*)g,
        (__attribute__((address_space(3))) unsigned int*)l, 16, 0, 0);
}

// ---------------- weight prep (hi+lo planes) ----------------
// Wq/Wk/Wv [L][8][512][64] f32 -> [L][1536][512] bf16 x2 (row = which*512+h*64+k, col = d)
__global__ __launch_bounds__(256)
void pack_qkv(const float* __restrict__ Wq, const float* __restrict__ Wk,
              const float* __restrict__ Wv, bf16* __restrict__ oh, bf16* __restrict__ ol) {
    size_t i = (size_t)blockIdx.x * 256 + threadIdx.x;
    int d = i & 511;
    size_t rr = i >> 9;
    int row = (int)(rr % 1536);
    int lay = (int)(rr / 1536);
    int which = row >> 9, hh = (row >> 6) & 7, k = row & 63;
    const float* W = which == 0 ? Wq : which == 1 ? Wk : Wv;
    float v = W[(((size_t)lay * 8 + hh) * 512 + d) * 64 + k];
    split2(v, oh[i], ol[i]);
}

// in [L][R][C] f32 -> out [L][C][R] bf16 x2
__global__ __launch_bounds__(256)
void transpose_w(const float* __restrict__ in, bf16* __restrict__ oh,
                 bf16* __restrict__ ol, int R, int C) {
    size_t i = (size_t)blockIdx.x * 256 + threadIdx.x;
    int r = (int)(i % R);
    size_t t = i / R;
    int c = (int)(t % C);
    int lay = (int)(t / C);
    split2(in[((size_t)lay * R + r) * C + c], oh[i], ol[i]);
}

// ---------------- embed ----------------
__global__ __launch_bounds__(512)
void embed_kernel(const float* __restrict__ x, const float* __restrict__ We,
                  const float* __restrict__ be, float* __restrict__ h,
                  bf16* __restrict__ hh, bf16* __restrict__ hl) {
    int row = blockIdx.x, d = threadIdx.x;
    const float* xr = x + (size_t)row * 8;
    float acc = be[d];
#pragma unroll
    for (int c = 0; c < 8; c++) acc += xr[c] * We[c * DIM + d];
    size_t idx = (size_t)row * DIM + d;
    h[idx] = acc;
    split2(acc, hh[idx], hl[idx]);
}

// ---------------- split-bf16 3-term MFMA GEMM, 128x128 tile, BK=32 ----------------
// A = Ah+Al [M][K]; B^T = Bh+Bl [N][K]. C = Ah Bh + Al Bh + Ah Bl (f32 acc).
// OUT=0: f32 (+bias) -> O0 [M][N]
// OUT=1: bias+relu -> hi/lo bf16 planes O0,O1 [M][N]
// OUT=2: QKV: cols [0,512)->Q O0, [512,1024)->K O1 (bf16 [M][512]),
//        [1024,1536): V transposed -> O2 [B][8][64][512] bf16
template<int OUT>
__global__ __launch_bounds__(256)
void gemm_bf16(const bf16* __restrict__ Ah, const bf16* __restrict__ Al,
               const bf16* __restrict__ Bh, const bf16* __restrict__ Bl,
               const float* __restrict__ bias,
               void* __restrict__ O0, void* __restrict__ O1, void* __restrict__ O2,
               int M, int N, int K) {
    __shared__ bf16 Ash[4096], Asl[4096];   // [128 rows][32 k]
    __shared__ bf16 Bsh[4096], Bsl[4096];
    const int row0 = blockIdx.y * 128, col0 = blockIdx.x * 128;
    const int tid = threadIdx.x, l = tid & 63, w = tid >> 6;
    const int wr = w >> 1, wc = w & 1;
    const int fr = l & 15, fq = l >> 4;
    const int srow = l >> 2, skg = (l & 3) * 8;

    f32x4 acc[4][4] = {};
    const size_t aoff = (size_t)(row0 + w * 32 + srow) * K + skg;
    const size_t boff = (size_t)(col0 + w * 32 + srow) * K + skg;

    for (int k0 = 0; k0 < K; k0 += 32) {
        __syncthreads();   // previous tile's reads complete
        gload_lds16(Ah + aoff + k0,          &Ash[(w * 2 + 0) * 512]);
        gload_lds16(Ah + aoff + 16 * K + k0, &Ash[(w * 2 + 1) * 512]);
        gload_lds16(Al + aoff + k0,          &Asl[(w * 2 + 0) * 512]);
        gload_lds16(Al + aoff + 16 * K + k0, &Asl[(w * 2 + 1) * 512]);
        gload_lds16(Bh + boff + k0,          &Bsh[(w * 2 + 0) * 512]);
        gload_lds16(Bh + boff + 16 * K + k0, &Bsh[(w * 2 + 1) * 512]);
        gload_lds16(Bl + boff + k0,          &Bsl[(w * 2 + 0) * 512]);
        gload_lds16(Bl + boff + 16 * K + k0, &Bsl[(w * 2 + 1) * 512]);
        __syncthreads();   // vmcnt drained at barrier: staging landed
        short8 ah[4], al[4], bh[4], bl[4];
#pragma unroll
        for (int i = 0; i < 4; i++) {
            int idx = (wr * 64 + i * 16 + fr) * 32 + fq * 8;
            ah[i] = *(const short8*)&Ash[idx];
            al[i] = *(const short8*)&Asl[idx];
        }
#pragma unroll
        for (int j = 0; j < 4; j++) {
            int idx = (wc * 64 + j * 16 + fr) * 32 + fq * 8;
            bh[j] = *(const short8*)&Bsh[idx];
            bl[j] = *(const short8*)&Bsl[idx];
        }
#pragma unroll
        for (int i = 0; i < 4; i++)
#pragma unroll
            for (int j = 0; j < 4; j++) {
                acc[i][j] = mfma_bf16(ah[i], bh[j], acc[i][j]);
                acc[i][j] = mfma_bf16(al[i], bh[j], acc[i][j]);
                acc[i][j] = mfma_bf16(ah[i], bl[j], acc[i][j]);
            }
    }

    if (OUT == 0) {
        float* C = (float*)O0;
#pragma unroll
        for (int j = 0; j < 4; j++) {
            int gcol = col0 + wc * 64 + j * 16 + fr;
            float bv = bias ? bias[gcol] : 0.f;
#pragma unroll
            for (int i = 0; i < 4; i++) {
                int gr = row0 + wr * 64 + i * 16 + fq * 4;
#pragma unroll
                for (int r = 0; r < 4; r++)
                    C[(size_t)(gr + r) * N + gcol] = acc[i][j][r] + bv;
            }
        }
    } else if (OUT == 1) {
        bf16* Chi = (bf16*)O0; bf16* Clo = (bf16*)O1;
#pragma unroll
        for (int j = 0; j < 4; j++) {
            int gcol = col0 + wc * 64 + j * 16 + fr;
            float bv = bias[gcol];
#pragma unroll
            for (int i = 0; i < 4; i++) {
                int gr = row0 + wr * 64 + i * 16 + fq * 4;
#pragma unroll
                for (int r = 0; r < 4; r++) {
                    float v = fmaxf(acc[i][j][r] + bv, 0.f);
                    size_t idx = (size_t)(gr + r) * N + gcol;
                    split2(v, Chi[idx], Clo[idx]);
                }
            }
        }
    } else {
        bf16* Qo = (bf16*)O0; bf16* Ko = (bf16*)O1; bf16* Vo = (bf16*)O2;
#pragma unroll
        for (int j = 0; j < 4; j++) {
            int gcol = col0 + wc * 64 + j * 16 + fr;
            if (gcol < 1024) {
                bf16* dst = gcol < 512 ? Qo : Ko;
                int cc = gcol & 511;
#pragma unroll
                for (int i = 0; i < 4; i++) {
                    int gr = row0 + wr * 64 + i * 16 + fq * 4;
#pragma unroll
                    for (int r = 0; r < 4; r++)
                        dst[(size_t)(gr + r) * 512 + cc] = __float2bfloat16(acc[i][j][r]);
                }
            } else {
                int hh = (gcol - 1024) >> 6, v = gcol & 63;
#pragma unroll
                for (int i = 0; i < 4; i++) {
                    int gr = row0 + wr * 64 + i * 16 + fq * 4;
                    int b = gr >> 9, n = gr & 511;
                    short4v sv;
#pragma unroll
                    for (int r = 0; r < 4; r++) sv[r] = f2b(acc[i][j][r]);
                    *(short4v*)&Vo[(((size_t)b * 8 + hh) * 64 + v) * 512 + n] = sv;
                }
            }
        }
    }
}

// ---------------- MFMA attention ----------------
__global__ __launch_bounds__(256)
void attn_mfma(const bf16* __restrict__ Q, const bf16* __restrict__ Kb,
               const bf16* __restrict__ Vt, const int* __restrict__ mask,
               bf16* __restrict__ att_hi, bf16* __restrict__ att_lo) {
    const int q0 = blockIdx.x * 16, b = blockIdx.y, hd = blockIdx.z;
    __shared__ float S[16][516];
    __shared__ float red1[16][16], red2[16][16];
    const int tid = threadIdx.x, l = tid & 63, w = tid >> 6;
    const int fr = l & 15, fq = l >> 4;

    const size_t qoff = ((size_t)b * NSEQ + q0) * DIM + hd * 64;
    short8 qa0 = *(const short8*)(Q + qoff + (size_t)fr * DIM + fq * 8);
    short8 qa1 = *(const short8*)(Q + qoff + (size_t)fr * DIM + 32 + fq * 8);
    const size_t kbase = (size_t)b * NSEQ * DIM + hd * 64;
#pragma unroll
    for (int f = 0; f < 8; f++) {
        int n0 = w * 128 + f * 16;
        const bf16* kp = Kb + kbase + (size_t)(n0 + fr) * DIM;
        short8 k0v = *(const short8*)(kp + fq * 8);
        short8 k1v = *(const short8*)(kp + 32 + fq * 8);
        f32x4 acc = {};
        acc = mfma_bf16(qa0, k0v, acc);
        acc = mfma_bf16(qa1, k1v, acc);
#pragma unroll
        for (int r = 0; r < 4; r++) S[fq * 4 + r][n0 + fr] = acc[r] * 0.125f;
    }
    __syncthreads();

    {
        const int r = tid >> 4, g = tid & 15;
        const int* mrow = mask + ((size_t)b * NSEQ + q0 + r) * NSEQ;
        float sv[32];
        float m = -INFINITY;
#pragma unroll
        for (int j = 0; j < 32; j++) {
            int n = j * 16 + g;
            float s = mrow[n] ? -INFINITY : S[r][n];
            sv[j] = s;
            m = fmaxf(m, s);
        }
        red1[r][g] = m;
        __syncthreads();
#pragma unroll
        for (int t = 0; t < 16; t++) m = fmaxf(m, red1[r][t]);
        float sum = 0.f;
#pragma unroll
        for (int j = 0; j < 32; j++) { float p = expf(sv[j] - m); sv[j] = p; sum += p; }
        red2[r][g] = sum;
        __syncthreads();
        float tot = 0.f;
#pragma unroll
        for (int t = 0; t < 16; t++) tot += red2[r][t];
        float inv = 1.f / tot;
#pragma unroll
        for (int j = 0; j < 32; j++) S[r][j * 16 + g] = sv[j] * inv;
    }
    __syncthreads();

    f32x4 oacc = {};
    const size_t vtb = ((size_t)b * 8 + hd) * 64 * 512;
#pragma unroll
    for (int ks = 0; ks < 16; ks++) {
        float4 p0 = *(const float4*)&S[fr][ks * 32 + fq * 8];
        float4 p1 = *(const float4*)&S[fr][ks * 32 + fq * 8 + 4];
        short8 pa;
        pa[0] = f2b(p0.x); pa[1] = f2b(p0.y); pa[2] = f2b(p0.z); pa[3] = f2b(p0.w);
        pa[4] = f2b(p1.x); pa[5] = f2b(p1.y); pa[6] = f2b(p1.z); pa[7] = f2b(p1.w);
        short8 vb = *(const short8*)(Vt + vtb + (size_t)(w * 16 + fr) * 512 + ks * 32 + fq * 8);
        oacc = mfma_bf16(pa, vb, oacc);
    }
#pragma unroll
    for (int r = 0; r < 4; r++) {
        size_t idx = ((size_t)b * NSEQ + q0 + fq * 4 + r) * DIM + hd * 64 + w * 16 + fr;
        split2(oacc[r], att_hi[idx], att_lo[idx]);
    }
}

// ---------------- BN ----------------
__global__ __launch_bounds__(512)
void bn_stats(float* __restrict__ h, const float* __restrict__ delta,
              float* __restrict__ sums) {
    const int c = threadIdx.x;
    float ps = 0.f, pq = 0.f;
    for (int r = blockIdx.x; r < BN_ROWS; r += gridDim.x) {
        size_t idx = (size_t)r * DIM + c;
        float v = h[idx] + delta[idx];
        h[idx] = v;
        ps += v;
        pq += v * v;
    }
    atomicAdd(&sums[c], ps);
    atomicAdd(&sums[DIM + c], pq);
}

__global__ __launch_bounds__(256)
void bn_apply(float* __restrict__ h, bf16* __restrict__ hh, bf16* __restrict__ hl,
              const float* __restrict__ sums, const float* __restrict__ g,
              const float* __restrict__ bt) {
    size_t idx = (size_t)blockIdx.x * 256 + threadIdx.x;
    int c = idx & (DIM - 1);
    float mu = sums[c] * (1.f / BN_ROWS);
    float var = sums[DIM + c] * (1.f / BN_ROWS) - mu * mu;
    float v = (h[idx] - mu) * rsqrtf(var + 1e-5f) * g[c] + bt[c];
    h[idx] = v;
    split2(v, hh[idx], hl[idx]);
}

// ---------------- outputs ----------------
__global__ __launch_bounds__(256)
void copy_kernel(const float* __restrict__ src, float* __restrict__ dst) {
    size_t idx = (size_t)blockIdx.x * 256 + threadIdx.x;
    dst[idx] = src[idx];
}

__global__ __launch_bounds__(512)
void mean_kernel(const float* __restrict__ h, float* __restrict__ out) {
    int b = blockIdx.x, d = threadIdx.x;
    float acc = 0.f;
    for (int n = 0; n < NSEQ; n++) acc += h[((size_t)b * NSEQ + n) * DIM + d];
    out[(size_t)b * DIM + d] = acc * (1.f / NSEQ);
}

extern "C" void kernel_launch(void* const* d_in, const int* in_sizes, int n_in,
                              void* d_out, int out_size, void* d_ws, size_t ws_size,
                              hipStream_t stream) {
    const float* x   = (const float*)d_in[0];
    const int*   mask= (const int*)d_in[1];
    const float* We  = (const float*)d_in[2];
    const float* be  = (const float*)d_in[3];
    const float* Wq  = (const float*)d_in[4];
    const float* Wk  = (const float*)d_in[5];
    const float* Wv  = (const float*)d_in[6];
    const float* Wo  = (const float*)d_in[7];
    const float* g1  = (const float*)d_in[8];
    const float* bt1 = (const float*)d_in[9];
    const float* g2  = (const float*)d_in[10];
    const float* bt2 = (const float*)d_in[11];
    const float* W1  = (const float*)d_in[12];
    const float* bf1 = (const float*)d_in[13];
    const float* W2  = (const float*)d_in[14];
    const float* bf2 = (const float*)d_in[15];
    float* out = (float*)d_out;

    const size_t MiB = 1ull << 20;
    char* base = (char*)d_ws;
    float* h      = (float*)base;                   // 32 MiB
    bf16*  hbf_h  = (bf16*)(base + 32 * MiB);       // 16
    bf16*  hbf_l  = (bf16*)(base + 48 * MiB);       // 16
    bf16*  Qbf    = (bf16*)(base + 64 * MiB);       // 16
    bf16*  Kbf    = (bf16*)(base + 80 * MiB);       // 16
    bf16*  Vt     = (bf16*)(base + 96 * MiB);       // 16
    float* proj   = (float*)(base + 64 * MiB);      // 32 (reuses Qbf+Kbf)
    bf16*  att_h  = (bf16*)(base + 112 * MiB);      // 16
    bf16*  att_l  = (bf16*)(base + 128 * MiB);      // 16
    bf16*  ffh_h  = att_h;                          // reuse (4096x2048 = 16MiB)
    bf16*  ffh_l  = att_l;
    float* stats  = (float*)(base + 144 * MiB);     // 4 KiB
    bf16*  wqkv_h = (bf16*)(base + 144 * MiB + 8192);
    bf16*  wqkv_l = wqkv_h + (size_t)4 * 1536 * 512;
    bf16*  wo_h   = wqkv_l + (size_t)4 * 1536 * 512;
    bf16*  wo_l   = wo_h   + (size_t)4 * 512 * 512;
    bf16*  w1t_h  = wo_l   + (size_t)4 * 512 * 512;
    bf16*  w1t_l  = w1t_h  + (size_t)4 * 2048 * 512;
    bf16*  w2t_h  = w1t_l  + (size_t)4 * 2048 * 512;
    bf16*  w2t_l  = w2t_h  + (size_t)4 * 2048 * 512;

    pack_qkv<<<dim3(4 * 1536 * 512 / 256), dim3(256), 0, stream>>>(Wq, Wk, Wv, wqkv_h, wqkv_l);
    transpose_w<<<dim3(4 * 512 * 512 / 256), dim3(256), 0, stream>>>(Wo, wo_h, wo_l, 512, 512);
    transpose_w<<<dim3(4 * 512 * 2048 / 256), dim3(256), 0, stream>>>(W1, w1t_h, w1t_l, 512, 2048);
    transpose_w<<<dim3(4 * 2048 * 512 / 256), dim3(256), 0, stream>>>(W2, w2t_h, w2t_l, 2048, 512);

    embed_kernel<<<dim3(BN_ROWS), dim3(512), 0, stream>>>(x, We, be, h, hbf_h, hbf_l);

    for (int l = 0; l < LAYERS; l++) {
        gemm_bf16<2><<<dim3(1536 / 128, 128), dim3(256), 0, stream>>>(
            hbf_h, hbf_l, wqkv_h + (size_t)l * 1536 * 512, wqkv_l + (size_t)l * 1536 * 512,
            nullptr, Qbf, Kbf, Vt, BN_ROWS, 1536, 512);

        attn_mfma<<<dim3(NSEQ / 16, BATCH, 8), dim3(256), 0, stream>>>(
            Qbf, Kbf, Vt, mask, att_h, att_l);

        gemm_bf16<0><<<dim3(512 / 128, 128), dim3(256), 0, stream>>>(
            att_h, att_l, wo_h + (size_t)l * 512 * 512, wo_l + (size_t)l * 512 * 512,
            nullptr, proj, nullptr, nullptr, BN_ROWS, 512, 512);

        hipMemsetAsync(stats, 0, 1024 * sizeof(float), stream);
        bn_stats<<<dim3(128), dim3(512), 0, stream>>>(h, proj, stats);
        bn_apply<<<dim3(BN_ROWS * DIM / 256), dim3(256), 0, stream>>>(
            h, hbf_h, hbf_l, stats, g1 + l * DIM, bt1 + l * DIM);

        for (int ch = 0; ch < 4; ch++) {
            size_t r0 = (size_t)ch * 4096;
            gemm_bf16<1><<<dim3(FF / 128, 4096 / 128), dim3(256), 0, stream>>>(
                hbf_h + r0 * DIM, hbf_l + r0 * DIM,
                w1t_h + (size_t)l * FF * DIM, w1t_l + (size_t)l * FF * DIM,
                bf1 + (size_t)l * FF, ffh_h, ffh_l, nullptr, 4096, FF, DIM);
            gemm_bf16<0><<<dim3(DIM / 128, 4096 / 128), dim3(256), 0, stream>>>(
                ffh_h, ffh_l,
                w2t_h + (size_t)l * DIM * FF, w2t_l + (size_t)l * DIM * FF,
                bf2 + (size_t)l * DIM, proj + r0 * DIM, nullptr, nullptr, 4096, DIM, FF);
        }

        hipMemsetAsync(stats, 0, 1024 * sizeof(float), stream);
        bn_stats<<<dim3(128), dim3(512), 0, stream>>>(h, proj, stats);
        bn_apply<<<dim3(BN_ROWS * DIM / 256), dim3(256), 0, stream>>>(
            h, hbf_h, hbf_l, stats, g2 + l * DIM, bt2 + l * DIM);
    }

    copy_kernel<<<dim3(BN_ROWS * DIM / 256), dim3(256), 0, stream>>>(h, out);
    mean_kernel<<<dim3(BATCH), dim3(512), 0, stream>>>(h, out + (size_t)BN_ROWS * DIM);
}

// Round 4
// 2502.554 us; speedup vs baseline: 7.3204x; 1.4652x over previous
//
#include <hip/hip_runtime.h>
#include <hip/hip_bf16.h>
#include <math.h>

#define BN_ROWS 16384   // B*N
#define DIM 512
#define FF 2048
#define LAYERS 4
#define NSEQ 512
#define BATCH 32

typedef __attribute__((ext_vector_type(8))) short short8;
typedef __attribute__((ext_vector_type(4))) short short4v;
typedef __attribute__((ext_vector_type(4))) float f32x4;
typedef __hip_bfloat16 bf16;
typedef unsigned long long u64;

__device__ __forceinline__ short f2b(float x) {
    bf16 b = __float2bfloat16(x);
    return *reinterpret_cast<short*>(&b);
}
__device__ __forceinline__ void split2(float v, bf16& hi, bf16& lo) {
    hi = __float2bfloat16(v);
    lo = __float2bfloat16(v - __bfloat162float(hi));
}
__device__ __forceinline__ f32x4 mfma_bf16(short8 a, short8 b, f32x4 c) {
    return __builtin_amdgcn_mfma_f32_16x16x32_bf16(a, b, c, 0, 0, 0);
}
__device__ __forceinline__ void gload_lds16(const bf16* g, bf16* l) {
    __builtin_amdgcn_global_load_lds(
        (const __attribute__((address_space(1))) unsigned int*)g,
        (__attribute__((address_space(3))) unsigned int*)l, 16, 0, 0);
}

// ---------------- weight prep (hi+lo planes) ----------------
__global__ __launch_bounds__(256)
void pack_qkv(const float* __restrict__ Wq, const float* __restrict__ Wk,
              const float* __restrict__ Wv, bf16* __restrict__ oh, bf16* __restrict__ ol) {
    size_t i = (size_t)blockIdx.x * 256 + threadIdx.x;
    int d = i & 511;
    size_t rr = i >> 9;
    int row = (int)(rr % 1536);
    int lay = (int)(rr / 1536);
    int which = row >> 9, hh = (row >> 6) & 7, k = row & 63;
    const float* W = which == 0 ? Wq : which == 1 ? Wk : Wv;
    float v = W[(((size_t)lay * 8 + hh) * 512 + d) * 64 + k];
    split2(v, oh[i], ol[i]);
}

__global__ __launch_bounds__(256)
void transpose_w(const float* __restrict__ in, bf16* __restrict__ oh,
                 bf16* __restrict__ ol, int R, int C) {
    size_t i = (size_t)blockIdx.x * 256 + threadIdx.x;
    int r = (int)(i % R);
    size_t t = i / R;
    int c = (int)(t % C);
    int lay = (int)(t / C);
    split2(in[((size_t)lay * R + r) * C + c], oh[i], ol[i]);
}

// mask [B][N][N] int -> bits [B][N][8] u64 via wave ballot (bit l = col l of 64-chunk)
__global__ __launch_bounds__(256)
void pack_mask(const int* __restrict__ mask, u64* __restrict__ pm) {
    int wid = (blockIdx.x * 256 + threadIdx.x) >> 6;   // 0..2047
    int lane = threadIdx.x & 63;
    for (int i = 0; i < 64; i++) {
        size_t word = (size_t)wid * 64 + i;            // 131072 words total
        u64 bal = __ballot(mask[word * 64 + lane] != 0);
        if (lane == 0) pm[word] = bal;
    }
}

// ---------------- embed ----------------
__global__ __launch_bounds__(512)
void embed_kernel(const float* __restrict__ x, const float* __restrict__ We,
                  const float* __restrict__ be, float* __restrict__ h,
                  bf16* __restrict__ hh, bf16* __restrict__ hl) {
    int row = blockIdx.x, d = threadIdx.x;
    const float* xr = x + (size_t)row * 8;
    float acc = be[d];
#pragma unroll
    for (int c = 0; c < 8; c++) acc += xr[c] * We[c * DIM + d];
    size_t idx = (size_t)row * DIM + d;
    h[idx] = acc;
    split2(acc, hh[idx], hl[idx]);
}

// ---------------- split-bf16 3-term MFMA GEMM, 128x128 tile, BK=32 ----------------
// OUT=1: bias+relu -> hi/lo bf16 planes O0,O1
// OUT=2: QKV split (Q->O0, K->O1, V transposed ->O2)
// OUT=3: residual+BN-stats: O0 = h (f32, in/out, h+=acc+bias), O1 = stats (sum,sumsq)
template<int OUT>
__global__ __launch_bounds__(256)
void gemm_bf16(const bf16* __restrict__ Ah, const bf16* __restrict__ Al,
               const bf16* __restrict__ Bh, const bf16* __restrict__ Bl,
               const float* __restrict__ bias,
               void* __restrict__ O0, void* __restrict__ O1, void* __restrict__ O2,
               int M, int N, int K) {
    __shared__ bf16 Ash[4096], Asl[4096];
    __shared__ bf16 Bsh[4096], Bsl[4096];
    const int row0 = blockIdx.y * 128, col0 = blockIdx.x * 128;
    const int tid = threadIdx.x, l = tid & 63, w = tid >> 6;
    const int wr = w >> 1, wc = w & 1;
    const int fr = l & 15, fq = l >> 4;
    const int srow = l >> 2, skg = (l & 3) * 8;

    f32x4 acc[4][4] = {};
    const size_t aoff = (size_t)(row0 + w * 32 + srow) * K + skg;
    const size_t boff = (size_t)(col0 + w * 32 + srow) * K + skg;

    for (int k0 = 0; k0 < K; k0 += 32) {
        __syncthreads();
        gload_lds16(Ah + aoff + k0,          &Ash[(w * 2 + 0) * 512]);
        gload_lds16(Ah + aoff + 16 * K + k0, &Ash[(w * 2 + 1) * 512]);
        gload_lds16(Al + aoff + k0,          &Asl[(w * 2 + 0) * 512]);
        gload_lds16(Al + aoff + 16 * K + k0, &Asl[(w * 2 + 1) * 512]);
        gload_lds16(Bh + boff + k0,          &Bsh[(w * 2 + 0) * 512]);
        gload_lds16(Bh + boff + 16 * K + k0, &Bsh[(w * 2 + 1) * 512]);
        gload_lds16(Bl + boff + k0,          &Bsl[(w * 2 + 0) * 512]);
        gload_lds16(Bl + boff + 16 * K + k0, &Bsl[(w * 2 + 1) * 512]);
        __syncthreads();
        short8 ah[4], al[4], bh[4], bl[4];
#pragma unroll
        for (int i = 0; i < 4; i++) {
            int idx = (wr * 64 + i * 16 + fr) * 32 + fq * 8;
            ah[i] = *(const short8*)&Ash[idx];
            al[i] = *(const short8*)&Asl[idx];
        }
#pragma unroll
        for (int j = 0; j < 4; j++) {
            int idx = (wc * 64 + j * 16 + fr) * 32 + fq * 8;
            bh[j] = *(const short8*)&Bsh[idx];
            bl[j] = *(const short8*)&Bsl[idx];
        }
#pragma unroll
        for (int i = 0; i < 4; i++)
#pragma unroll
            for (int j = 0; j < 4; j++) {
                acc[i][j] = mfma_bf16(ah[i], bh[j], acc[i][j]);
                acc[i][j] = mfma_bf16(al[i], bh[j], acc[i][j]);
                acc[i][j] = mfma_bf16(ah[i], bl[j], acc[i][j]);
            }
    }

    if (OUT == 1) {
        bf16* Chi = (bf16*)O0; bf16* Clo = (bf16*)O1;
#pragma unroll
        for (int j = 0; j < 4; j++) {
            int gcol = col0 + wc * 64 + j * 16 + fr;
            float bv = bias[gcol];
#pragma unroll
            for (int i = 0; i < 4; i++) {
                int gr = row0 + wr * 64 + i * 16 + fq * 4;
#pragma unroll
                for (int r = 0; r < 4; r++) {
                    float v = fmaxf(acc[i][j][r] + bv, 0.f);
                    size_t idx = (size_t)(gr + r) * N + gcol;
                    split2(v, Chi[idx], Clo[idx]);
                }
            }
        }
    } else if (OUT == 2) {
        bf16* Qo = (bf16*)O0; bf16* Ko = (bf16*)O1; bf16* Vo = (bf16*)O2;
#pragma unroll
        for (int j = 0; j < 4; j++) {
            int gcol = col0 + wc * 64 + j * 16 + fr;
            if (gcol < 1024) {
                bf16* dst = gcol < 512 ? Qo : Ko;
                int cc = gcol & 511;
#pragma unroll
                for (int i = 0; i < 4; i++) {
                    int gr = row0 + wr * 64 + i * 16 + fq * 4;
#pragma unroll
                    for (int r = 0; r < 4; r++)
                        dst[(size_t)(gr + r) * 512 + cc] = __float2bfloat16(acc[i][j][r]);
                }
            } else {
                int hh = (gcol - 1024) >> 6, v = gcol & 63;
#pragma unroll
                for (int i = 0; i < 4; i++) {
                    int gr = row0 + wr * 64 + i * 16 + fq * 4;
                    int b = gr >> 9, n = gr & 511;
                    short4v sv;
#pragma unroll
                    for (int r = 0; r < 4; r++) sv[r] = f2b(acc[i][j][r]);
                    *(short4v*)&Vo[(((size_t)b * 8 + hh) * 64 + v) * 512 + n] = sv;
                }
            }
        }
    } else {   // OUT == 3
        float* hres = (float*)O0;
        float* st   = (float*)O1;
#pragma unroll
        for (int j = 0; j < 4; j++) {
            int gcol = col0 + wc * 64 + j * 16 + fr;
            float bv = bias ? bias[gcol] : 0.f;
            float csum = 0.f, csq = 0.f;
#pragma unroll
            for (int i = 0; i < 4; i++) {
                int gr = row0 + wr * 64 + i * 16 + fq * 4;
#pragma unroll
                for (int r = 0; r < 4; r++) {
                    size_t idx = (size_t)(gr + r) * N + gcol;
                    float v = acc[i][j][r] + bv + hres[idx];
                    hres[idx] = v;
                    csum += v; csq += v * v;
                }
            }
            csum += __shfl_down(csum, 32, 64); csum += __shfl_down(csum, 16, 64);
            csq  += __shfl_down(csq,  32, 64); csq  += __shfl_down(csq,  16, 64);
            if (fq == 0) {
                atomicAdd(&st[gcol], csum);
                atomicAdd(&st[gcol + 512], csq);
            }
        }
    }
}

// ---------------- flash attention: 128 q-rows/block, 4 independent waves ----------------
__global__ __launch_bounds__(256)
void attn_flash(const bf16* __restrict__ Q, const bf16* __restrict__ Kg,
                const bf16* __restrict__ Vt, const u64* __restrict__ pmask,
                bf16* __restrict__ att_h, bf16* __restrict__ att_l) {
    // bijective XCD swizzle: 1024 blocks, consecutive wgid share (b,hd)
    int id = blockIdx.x;
    int wgid = (id & 7) * 128 + (id >> 3);
    int qc = wgid & 3;
    int gid = wgid >> 2;
    int b = gid & 31, hd = gid >> 5;

    __shared__ short Plds[4][1024];   // per wave: 16x64 bf16, XOR-swizzled

    const int tid = threadIdx.x, w = tid >> 6, l = tid & 63;
    const int fr = l & 15, fq = l >> 4;

    const int brow = qc * 128 + w * 32;                      // within batch b
    const size_t qbase = ((size_t)b * NSEQ + brow) * DIM + hd * 64;
    short8 qa[2][2];
#pragma unroll
    for (int sub = 0; sub < 2; sub++)
#pragma unroll
        for (int ks = 0; ks < 2; ks++)
            qa[sub][ks] = *(const short8*)(Q + qbase + (size_t)(sub * 16 + fr) * DIM + ks * 32 + fq * 8);

    const size_t kbase = (size_t)b * NSEQ * DIM + hd * 64;
    const size_t vtb = ((size_t)b * 8 + hd) * 64 * 512;
    const u64* mrow = pmask + ((size_t)b * NSEQ + brow) * 8;

    float m[2][4], lsum[2][4];
    f32x4 O[2][4];
#pragma unroll
    for (int s = 0; s < 2; s++)
#pragma unroll
        for (int r = 0; r < 4; r++) {
            m[s][r] = -1e30f; lsum[s][r] = 0.f;
            O[s][r] = (f32x4){0.f, 0.f, 0.f, 0.f};
        }

    char* Pb = (char*)&Plds[w][0];

    for (int c = 0; c < 8; c++) {
        const int n0 = c * 64;
        short8 kb[4][2];
#pragma unroll
        for (int nt = 0; nt < 4; nt++)
#pragma unroll
            for (int ks = 0; ks < 2; ks++)
                kb[nt][ks] = *(const short8*)(Kg + kbase + (size_t)(n0 + nt * 16 + fr) * DIM + ks * 32 + fq * 8);

        f32x4 ps[2][4];
#pragma unroll
        for (int sub = 0; sub < 2; sub++)
#pragma unroll
            for (int nt = 0; nt < 4; nt++) {
                f32x4 a = {};
                a = mfma_bf16(qa[sub][0], kb[nt][0], a);
                a = mfma_bf16(qa[sub][1], kb[nt][1], a);
                ps[sub][nt] = a;
            }
        // scale + mask (C layout: row = fq*4+rr, col = nt*16+fr)
#pragma unroll
        for (int sub = 0; sub < 2; sub++)
#pragma unroll
            for (int rr = 0; rr < 4; rr++) {
                u64 bits = mrow[(size_t)(sub * 16 + fq * 4 + rr) * 8 + c];
#pragma unroll
                for (int nt = 0; nt < 4; nt++) {
                    float s = ps[sub][nt][rr] * 0.125f;
                    ps[sub][nt][rr] = ((bits >> (nt * 16 + fr)) & 1ull) ? -INFINITY : s;
                }
            }

        short8 vb[4][2];
#pragma unroll
        for (int vt = 0; vt < 4; vt++)
#pragma unroll
            for (int ks = 0; ks < 2; ks++)
                vb[vt][ks] = *(const short8*)(Vt + vtb + (size_t)(vt * 16 + fr) * 512 + n0 + ks * 32 + fq * 8);

#pragma unroll
        for (int sub = 0; sub < 2; sub++) {
            float cm[4], sc[4], cs[4];
#pragma unroll
            for (int rr = 0; rr < 4; rr++) {
                float v = fmaxf(fmaxf(ps[sub][0][rr], ps[sub][1][rr]),
                                fmaxf(ps[sub][2][rr], ps[sub][3][rr]));
#pragma unroll
                for (int msk = 1; msk < 16; msk <<= 1)
                    v = fmaxf(v, __shfl_xor(v, msk, 64));
                cm[rr] = v;
            }
#pragma unroll
            for (int rr = 0; rr < 4; rr++) {
                float mn = fmaxf(m[sub][rr], cm[rr]);
                sc[rr] = __expf(m[sub][rr] - mn);
                m[sub][rr] = mn;
                cs[rr] = 0.f;
            }
#pragma unroll
            for (int nt = 0; nt < 4; nt++)
#pragma unroll
                for (int rr = 0; rr < 4; rr++) {
                    float p = __expf(ps[sub][nt][rr] - m[sub][rr]);
                    ps[sub][nt][rr] = p;
                    cs[rr] += p;
                }
#pragma unroll
            for (int rr = 0; rr < 4; rr++) {
#pragma unroll
                for (int msk = 1; msk < 16; msk <<= 1)
                    cs[rr] += __shfl_xor(cs[rr], msk, 64);
                lsum[sub][rr] = lsum[sub][rr] * sc[rr] + cs[rr];
            }
#pragma unroll
            for (int vt = 0; vt < 4; vt++)
#pragma unroll
                for (int rr = 0; rr < 4; rr++)
                    O[sub][vt][rr] *= sc[rr];
            // P -> LDS (bf16), row-XOR swizzle on byte bits 4-6
#pragma unroll
            for (int nt = 0; nt < 4; nt++)
#pragma unroll
                for (int rr = 0; rr < 4; rr++) {
                    int row = fq * 4 + rr;
                    int byte = ((row * 64 + nt * 16 + fr) * 2) ^ ((row & 7) << 4);
                    *(short*)(Pb + byte) = f2b(ps[sub][nt][rr]);
                }
            short8 pa[2];
#pragma unroll
            for (int ks = 0; ks < 2; ks++) {
                int byte = ((fr * 64 + ks * 32 + fq * 8) * 2) ^ ((fr & 7) << 4);
                pa[ks] = *(const short8*)(Pb + byte);
            }
#pragma unroll
            for (int vt = 0; vt < 4; vt++) {
                O[sub][vt] = mfma_bf16(pa[0], vb[vt][0], O[sub][vt]);
                O[sub][vt] = mfma_bf16(pa[1], vb[vt][1], O[sub][vt]);
            }
        }
    }
    // epilogue: O / l, split to hi/lo
#pragma unroll
    for (int sub = 0; sub < 2; sub++) {
        float inv[4];
#pragma unroll
        for (int rr = 0; rr < 4; rr++) inv[rr] = 1.f / lsum[sub][rr];
#pragma unroll
        for (int vt = 0; vt < 4; vt++)
#pragma unroll
            for (int rr = 0; rr < 4; rr++) {
                float v = O[sub][vt][rr] * inv[rr];
                size_t idx = ((size_t)b * NSEQ + brow + sub * 16 + fq * 4 + rr) * DIM
                             + hd * 64 + vt * 16 + fr;
                split2(v, att_h[idx], att_l[idx]);
            }
    }
}

// ---------------- BN apply (vectorized x4), optional fused final-out write ----------------
__global__ __launch_bounds__(256)
void bn_apply(float* __restrict__ h, bf16* __restrict__ hh, bf16* __restrict__ hl,
              const float* __restrict__ sums, const float* __restrict__ g,
              const float* __restrict__ bt, float* __restrict__ outp) {
    size_t i4 = (size_t)blockIdx.x * 256 + threadIdx.x;   // grid = BN_ROWS*DIM/4/256
    size_t idx = i4 * 4;
    int c = (int)(idx & (DIM - 1));
    float4 hv = *(float4*)&h[idx];
    float4 s4 = *(const float4*)&sums[c];
    float4 q4 = *(const float4*)&sums[DIM + c];
    float4 g4 = *(const float4*)&g[c];
    float4 b4 = *(const float4*)&bt[c];
    float o[4];
    const float invn = 1.f / BN_ROWS;
#pragma unroll
    for (int j = 0; j < 4; j++) {
        float mu = ((const float*)&s4)[j] * invn;
        float var = ((const float*)&q4)[j] * invn - mu * mu;
        float v = (((const float*)&hv)[j] - mu) * rsqrtf(var + 1e-5f)
                  * ((const float*)&g4)[j] + ((const float*)&b4)[j];
        o[j] = v;
    }
    *(float4*)&h[idx] = *(float4*)o;
    if (outp) *(float4*)&outp[idx] = *(float4*)o;
    short4v sh, sl;
#pragma unroll
    for (int j = 0; j < 4; j++) {
        bf16 bhi, blo;
        split2(o[j], bhi, blo);
        sh[j] = *(short*)&bhi; sl[j] = *(short*)&blo;
    }
    *(short4v*)&hh[idx] = sh;
    *(short4v*)&hl[idx] = sl;
}

// ---------------- mean over n (atomic partials) ----------------
__global__ __launch_bounds__(512)
void mean_kernel(const float* __restrict__ src, float* __restrict__ out2) {
    int b = blockIdx.x, seg = blockIdx.y, d = threadIdx.x;
    float acc = 0.f;
    for (int n = seg * 64; n < seg * 64 + 64; n++)
        acc += src[((size_t)b * NSEQ + n) * DIM + d];
    atomicAdd(&out2[b * DIM + d], acc * (1.f / NSEQ));
}

extern "C" void kernel_launch(void* const* d_in, const int* in_sizes, int n_in,
                              void* d_out, int out_size, void* d_ws, size_t ws_size,
                              hipStream_t stream) {
    const float* x   = (const float*)d_in[0];
    const int*   mask= (const int*)d_in[1];
    const float* We  = (const float*)d_in[2];
    const float* be  = (const float*)d_in[3];
    const float* Wq  = (const float*)d_in[4];
    const float* Wk  = (const float*)d_in[5];
    const float* Wv  = (const float*)d_in[6];
    const float* Wo  = (const float*)d_in[7];
    const float* g1  = (const float*)d_in[8];
    const float* bt1 = (const float*)d_in[9];
    const float* g2  = (const float*)d_in[10];
    const float* bt2 = (const float*)d_in[11];
    const float* W1  = (const float*)d_in[12];
    const float* bf1 = (const float*)d_in[13];
    const float* W2  = (const float*)d_in[14];
    const float* bf2 = (const float*)d_in[15];
    float* out = (float*)d_out;

    const size_t MiB = 1ull << 20;
    const size_t M1 = (size_t)BN_ROWS * DIM;
    char* base = (char*)d_ws;
    float* h      = (float*)base;                   // 0-32 MiB
    bf16*  hbf_h  = (bf16*)(base + 32 * MiB);
    bf16*  hbf_l  = (bf16*)(base + 48 * MiB);
    bf16*  Qbf    = (bf16*)(base + 64 * MiB);
    bf16*  Kbf    = (bf16*)(base + 80 * MiB);
    bf16*  Vt     = (bf16*)(base + 96 * MiB);
    bf16*  att_h  = (bf16*)(base + 112 * MiB);
    bf16*  att_l  = (bf16*)(base + 128 * MiB);
    bf16*  ffh_h  = (bf16*)(base + 64 * MiB);       // reuses Qbf+Kbf (8192x2048)
    bf16*  ffh_l  = (bf16*)(base + 112 * MiB);      // reuses att planes
    float* stats  = (float*)(base + 144 * MiB);     // 4 KiB
    u64*   pmask  = (u64*)(base + 144 * MiB + 65536);   // 1 MiB
    bf16*  wqkv_h = (bf16*)(base + 146 * MiB);
    bf16*  wqkv_l = wqkv_h + (size_t)4 * 1536 * 512;
    bf16*  wo_h   = wqkv_l + (size_t)4 * 1536 * 512;
    bf16*  wo_l   = wo_h   + (size_t)4 * 512 * 512;
    bf16*  w1t_h  = wo_l   + (size_t)4 * 512 * 512;
    bf16*  w1t_l  = w1t_h  + (size_t)4 * 2048 * 512;
    bf16*  w2t_h  = w1t_l  + (size_t)4 * 2048 * 512;
    bf16*  w2t_l  = w2t_h  + (size_t)4 * 2048 * 512;

    pack_qkv<<<dim3(4 * 1536 * 512 / 256), dim3(256), 0, stream>>>(Wq, Wk, Wv, wqkv_h, wqkv_l);
    transpose_w<<<dim3(4 * 512 * 512 / 256), dim3(256), 0, stream>>>(Wo, wo_h, wo_l, 512, 512);
    transpose_w<<<dim3(4 * 512 * 2048 / 256), dim3(256), 0, stream>>>(W1, w1t_h, w1t_l, 512, 2048);
    transpose_w<<<dim3(4 * 2048 * 512 / 256), dim3(256), 0, stream>>>(W2, w2t_h, w2t_l, 2048, 512);
    pack_mask<<<dim3(512), dim3(256), 0, stream>>>(mask, pmask);
    hipMemsetAsync(out + M1, 0, BATCH * DIM * sizeof(float), stream);

    embed_kernel<<<dim3(BN_ROWS), dim3(512), 0, stream>>>(x, We, be, h, hbf_h, hbf_l);

    for (int l = 0; l < LAYERS; l++) {
        gemm_bf16<2><<<dim3(1536 / 128, 128), dim3(256), 0, stream>>>(
            hbf_h, hbf_l, wqkv_h + (size_t)l * 1536 * 512, wqkv_l + (size_t)l * 1536 * 512,
            nullptr, Qbf, Kbf, Vt, BN_ROWS, 1536, 512);

        attn_flash<<<dim3(1024), dim3(256), 0, stream>>>(
            Qbf, Kbf, Vt, pmask, att_h, att_l);

        hipMemsetAsync(stats, 0, 1024 * sizeof(float), stream);
        gemm_bf16<3><<<dim3(512 / 128, 128), dim3(256), 0, stream>>>(
            att_h, att_l, wo_h + (size_t)l * 512 * 512, wo_l + (size_t)l * 512 * 512,
            nullptr, h, stats, nullptr, BN_ROWS, 512, 512);
        bn_apply<<<dim3(M1 / 1024), dim3(256), 0, stream>>>(
            h, hbf_h, hbf_l, stats, g1 + l * DIM, bt1 + l * DIM, nullptr);

        hipMemsetAsync(stats, 0, 1024 * sizeof(float), stream);
        for (int ch = 0; ch < 2; ch++) {
            size_t r0 = (size_t)ch * 8192;
            gemm_bf16<1><<<dim3(FF / 128, 8192 / 128), dim3(256), 0, stream>>>(
                hbf_h + r0 * DIM, hbf_l + r0 * DIM,
                w1t_h + (size_t)l * FF * DIM, w1t_l + (size_t)l * FF * DIM,
                bf1 + (size_t)l * FF, ffh_h, ffh_l, nullptr, 8192, FF, DIM);
            gemm_bf16<3><<<dim3(DIM / 128, 8192 / 128), dim3(256), 0, stream>>>(
                ffh_h, ffh_l,
                w2t_h + (size_t)l * DIM * FF, w2t_l + (size_t)l * DIM * FF,
                bf2 + (size_t)l * DIM, h + r0 * DIM, stats, nullptr, 8192, DIM, FF);
        }
        float* outp = (l == LAYERS - 1) ? out : nullptr;
        bn_apply<<<dim3(M1 / 1024), dim3(256), 0, stream>>>(
            h, hbf_h, hbf_l, stats, g2 + l * DIM, bt2 + l * DIM, outp);
    }

    mean_kernel<<<dim3(BATCH, 8), dim3(512), 0, stream>>>(out, out + M1);
}

// Round 5
// 1360.120 us; speedup vs baseline: 13.4691x; 1.8400x over previous
//
#include <hip/hip_runtime.h>
#include <hip/hip_fp16.h>
#include <math.h>

#define BN_ROWS 16384   // B*N
#define DIM 512
#define FF 2048
#define LAYERS 4
#define NSEQ 512
#define BATCH 32

typedef _Float16 f16;
typedef __attribute__((ext_vector_type(8))) _Float16 f16x8;
typedef __attribute__((ext_vector_type(4))) _Float16 f16x4;
typedef __attribute__((ext_vector_type(4))) float f32x4;
typedef unsigned long long u64;

__device__ __forceinline__ f32x4 mfma_f16(f16x8 a, f16x8 b, f32x4 c) {
    return __builtin_amdgcn_mfma_f32_16x16x32_f16(a, b, c, 0, 0, 0);
}
__device__ __forceinline__ void gload_lds16(const f16* g, f16* l) {
    __builtin_amdgcn_global_load_lds(
        (const __attribute__((address_space(1))) unsigned int*)g,
        (__attribute__((address_space(3))) unsigned int*)l, 16, 0, 0);
}

// ---------------- weight prep (single fp16 plane) ----------------
__global__ __launch_bounds__(256)
void pack_qkv(const float* __restrict__ Wq, const float* __restrict__ Wk,
              const float* __restrict__ Wv, f16* __restrict__ oh) {
    size_t i = (size_t)blockIdx.x * 256 + threadIdx.x;
    int d = i & 511;
    size_t rr = i >> 9;
    int row = (int)(rr % 1536);
    int lay = (int)(rr / 1536);
    int which = row >> 9, hh = (row >> 6) & 7, k = row & 63;
    const float* W = which == 0 ? Wq : which == 1 ? Wk : Wv;
    oh[i] = (f16)W[(((size_t)lay * 8 + hh) * 512 + d) * 64 + k];
}

__global__ __launch_bounds__(256)
void transpose_w(const float* __restrict__ in, f16* __restrict__ oh, int R, int C) {
    size_t i = (size_t)blockIdx.x * 256 + threadIdx.x;
    int r = (int)(i % R);
    size_t t = i / R;
    int c = (int)(t % C);
    int lay = (int)(t / C);
    oh[i] = (f16)in[((size_t)lay * R + r) * C + c];
}

// mask [B][N][N] int -> bits [B][N][8] u64
__global__ __launch_bounds__(256)
void pack_mask(const int* __restrict__ mask, u64* __restrict__ pm) {
    int wid = (blockIdx.x * 256 + threadIdx.x) >> 6;
    int lane = threadIdx.x & 63;
    for (int i = 0; i < 64; i++) {
        size_t word = (size_t)wid * 64 + i;
        u64 bal = __ballot(mask[word * 64 + lane] != 0);
        if (lane == 0) pm[word] = bal;
    }
}

// ---------------- embed ----------------
__global__ __launch_bounds__(512)
void embed_kernel(const float* __restrict__ x, const float* __restrict__ We,
                  const float* __restrict__ be, float* __restrict__ h,
                  f16* __restrict__ hf) {
    int row = blockIdx.x, d = threadIdx.x;
    const float* xr = x + (size_t)row * 8;
    float acc = be[d];
#pragma unroll
    for (int c = 0; c < 8; c++) acc += xr[c] * We[c * DIM + d];
    size_t idx = (size_t)row * DIM + d;
    h[idx] = acc;
    hf[idx] = (f16)acc;
}

// ---------------- fp16 MFMA GEMM, 128x128 tile, BK=32 (m97 structure) ----------------
// A [M][K] f16; Bt [N][K] f16.
// OUT=1: bias+relu -> f16 O0
// OUT=2: QKV split (Q->O0, K->O1 f16 [M][512]; V transposed -> O2 [B][8][64][512])
// OUT=3: residual+BN-stats: O0 = h f32 (h += acc + bias), O1 = stats (sum,sumsq)
template<int OUT>
__global__ __launch_bounds__(256)
void gemm_f16(const f16* __restrict__ A, const f16* __restrict__ Bt,
              const float* __restrict__ bias,
              void* __restrict__ O0, void* __restrict__ O1, void* __restrict__ O2,
              int M, int N, int K) {
    __shared__ f16 As[4096];   // [128 rows][32 k]
    __shared__ f16 Bs[4096];
    const int row0 = blockIdx.y * 128, col0 = blockIdx.x * 128;
    const int tid = threadIdx.x, l = tid & 63, w = tid >> 6;
    const int wr = w >> 1, wc = w & 1;
    const int fr = l & 15, fq = l >> 4;
    const int srow = l >> 2, skg = (l & 3) * 8;

    f32x4 acc[4][4] = {};
    const size_t aoff = (size_t)(row0 + w * 32 + srow) * K + skg;
    const size_t boff = (size_t)(col0 + w * 32 + srow) * K + skg;

    for (int k0 = 0; k0 < K; k0 += 32) {
        __syncthreads();
        gload_lds16(A + aoff + k0,           &As[(w * 2 + 0) * 512]);
        gload_lds16(A + aoff + 16 * K + k0,  &As[(w * 2 + 1) * 512]);
        gload_lds16(Bt + boff + k0,          &Bs[(w * 2 + 0) * 512]);
        gload_lds16(Bt + boff + 16 * K + k0, &Bs[(w * 2 + 1) * 512]);
        __syncthreads();
        f16x8 a[4], b[4];
#pragma unroll
        for (int i = 0; i < 4; i++)
            a[i] = *(const f16x8*)&As[(wr * 64 + i * 16 + fr) * 32 + fq * 8];
#pragma unroll
        for (int j = 0; j < 4; j++)
            b[j] = *(const f16x8*)&Bs[(wc * 64 + j * 16 + fr) * 32 + fq * 8];
#pragma unroll
        for (int i = 0; i < 4; i++)
#pragma unroll
            for (int j = 0; j < 4; j++)
                acc[i][j] = mfma_f16(a[i], b[j], acc[i][j]);
    }

    if (OUT == 1) {
        f16* C = (f16*)O0;
#pragma unroll
        for (int j = 0; j < 4; j++) {
            int gcol = col0 + wc * 64 + j * 16 + fr;
            float bv = bias[gcol];
#pragma unroll
            for (int i = 0; i < 4; i++) {
                int gr = row0 + wr * 64 + i * 16 + fq * 4;
#pragma unroll
                for (int r = 0; r < 4; r++)
                    C[(size_t)(gr + r) * N + gcol] = (f16)fmaxf(acc[i][j][r] + bv, 0.f);
            }
        }
    } else if (OUT == 2) {
        f16* Qo = (f16*)O0; f16* Ko = (f16*)O1; f16* Vo = (f16*)O2;
#pragma unroll
        for (int j = 0; j < 4; j++) {
            int gcol = col0 + wc * 64 + j * 16 + fr;
            if (gcol < 1024) {
                f16* dst = gcol < 512 ? Qo : Ko;
                int cc = gcol & 511;
#pragma unroll
                for (int i = 0; i < 4; i++) {
                    int gr = row0 + wr * 64 + i * 16 + fq * 4;
#pragma unroll
                    for (int r = 0; r < 4; r++)
                        dst[(size_t)(gr + r) * 512 + cc] = (f16)acc[i][j][r];
                }
            } else {
                int hh = (gcol - 1024) >> 6, v = gcol & 63;
#pragma unroll
                for (int i = 0; i < 4; i++) {
                    int gr = row0 + wr * 64 + i * 16 + fq * 4;
                    int b = gr >> 9, n = gr & 511;
                    f16x4 sv;
#pragma unroll
                    for (int r = 0; r < 4; r++) sv[r] = (f16)acc[i][j][r];
                    *(f16x4*)&Vo[(((size_t)b * 8 + hh) * 64 + v) * 512 + n] = sv;
                }
            }
        }
    } else {   // OUT == 3
        float* hres = (float*)O0;
        float* st   = (float*)O1;
#pragma unroll
        for (int j = 0; j < 4; j++) {
            int gcol = col0 + wc * 64 + j * 16 + fr;
            float bv = bias ? bias[gcol] : 0.f;
            float csum = 0.f, csq = 0.f;
#pragma unroll
            for (int i = 0; i < 4; i++) {
                int gr = row0 + wr * 64 + i * 16 + fq * 4;
#pragma unroll
                for (int r = 0; r < 4; r++) {
                    size_t idx = (size_t)(gr + r) * N + gcol;
                    float v = acc[i][j][r] + bv + hres[idx];
                    hres[idx] = v;
                    csum += v; csq += v * v;
                }
            }
            csum += __shfl_down(csum, 32, 64); csum += __shfl_down(csum, 16, 64);
            csq  += __shfl_down(csq,  32, 64); csq  += __shfl_down(csq,  16, 64);
            if (fq == 0) {
                atomicAdd(&st[gcol], csum);
                atomicAdd(&st[gcol + 512], csq);
            }
        }
    }
}

// ---------------- flash attention (fp16), 128 q-rows/block, 4 independent waves ----------------
__global__ __launch_bounds__(256)
void attn_flash(const f16* __restrict__ Q, const f16* __restrict__ Kg,
                const f16* __restrict__ Vt, const u64* __restrict__ pmask,
                f16* __restrict__ attf) {
    int id = blockIdx.x;
    int wgid = (id & 7) * 128 + (id >> 3);   // bijective XCD swizzle (1024 = 8*128)
    int qc = wgid & 3;
    int gid = wgid >> 2;
    int b = gid & 31, hd = gid >> 5;

    __shared__ f16 Plds[4][1024];   // per wave: 16x64 f16, XOR-swizzled

    const int tid = threadIdx.x, w = tid >> 6, l = tid & 63;
    const int fr = l & 15, fq = l >> 4;

    const int brow = qc * 128 + w * 32;
    const size_t qbase = ((size_t)b * NSEQ + brow) * DIM + hd * 64;
    f16x8 qa[2][2];
#pragma unroll
    for (int sub = 0; sub < 2; sub++)
#pragma unroll
        for (int ks = 0; ks < 2; ks++)
            qa[sub][ks] = *(const f16x8*)(Q + qbase + (size_t)(sub * 16 + fr) * DIM + ks * 32 + fq * 8);

    const size_t kbase = (size_t)b * NSEQ * DIM + hd * 64;
    const size_t vtb = ((size_t)b * 8 + hd) * 64 * 512;
    const u64* mrow = pmask + ((size_t)b * NSEQ + brow) * 8;

    float m[2][4], lsum[2][4];
    f32x4 O[2][4];
#pragma unroll
    for (int s = 0; s < 2; s++)
#pragma unroll
        for (int r = 0; r < 4; r++) {
            m[s][r] = -1e30f; lsum[s][r] = 0.f;
            O[s][r] = (f32x4){0.f, 0.f, 0.f, 0.f};
        }

    char* Pb = (char*)&Plds[w][0];

    for (int c = 0; c < 8; c++) {
        const int n0 = c * 64;
        f16x8 kb[4][2];
#pragma unroll
        for (int nt = 0; nt < 4; nt++)
#pragma unroll
            for (int ks = 0; ks < 2; ks++)
                kb[nt][ks] = *(const f16x8*)(Kg + kbase + (size_t)(n0 + nt * 16 + fr) * DIM + ks * 32 + fq * 8);

        f32x4 ps[2][4];
#pragma unroll
        for (int sub = 0; sub < 2; sub++)
#pragma unroll
            for (int nt = 0; nt < 4; nt++) {
                f32x4 a = {};
                a = mfma_f16(qa[sub][0], kb[nt][0], a);
                a = mfma_f16(qa[sub][1], kb[nt][1], a);
                ps[sub][nt] = a;
            }
#pragma unroll
        for (int sub = 0; sub < 2; sub++)
#pragma unroll
            for (int rr = 0; rr < 4; rr++) {
                u64 bits = mrow[(size_t)(sub * 16 + fq * 4 + rr) * 8 + c];
#pragma unroll
                for (int nt = 0; nt < 4; nt++) {
                    float s = ps[sub][nt][rr] * 0.125f;
                    ps[sub][nt][rr] = ((bits >> (nt * 16 + fr)) & 1ull) ? -INFINITY : s;
                }
            }

        f16x8 vb[4][2];
#pragma unroll
        for (int vt = 0; vt < 4; vt++)
#pragma unroll
            for (int ks = 0; ks < 2; ks++)
                vb[vt][ks] = *(const f16x8*)(Vt + vtb + (size_t)(vt * 16 + fr) * 512 + n0 + ks * 32 + fq * 8);

#pragma unroll
        for (int sub = 0; sub < 2; sub++) {
            float cm[4], sc[4], cs[4];
#pragma unroll
            for (int rr = 0; rr < 4; rr++) {
                float v = fmaxf(fmaxf(ps[sub][0][rr], ps[sub][1][rr]),
                                fmaxf(ps[sub][2][rr], ps[sub][3][rr]));
#pragma unroll
                for (int msk = 1; msk < 16; msk <<= 1)
                    v = fmaxf(v, __shfl_xor(v, msk, 64));
                cm[rr] = v;
            }
#pragma unroll
            for (int rr = 0; rr < 4; rr++) {
                float mn = fmaxf(m[sub][rr], cm[rr]);
                sc[rr] = __expf(m[sub][rr] - mn);
                m[sub][rr] = mn;
                cs[rr] = 0.f;
            }
#pragma unroll
            for (int nt = 0; nt < 4; nt++)
#pragma unroll
                for (int rr = 0; rr < 4; rr++) {
                    float p = __expf(ps[sub][nt][rr] - m[sub][rr]);
                    ps[sub][nt][rr] = p;
                    cs[rr] += p;
                }
#pragma unroll
            for (int rr = 0; rr < 4; rr++) {
#pragma unroll
                for (int msk = 1; msk < 16; msk <<= 1)
                    cs[rr] += __shfl_xor(cs[rr], msk, 64);
                lsum[sub][rr] = lsum[sub][rr] * sc[rr] + cs[rr];
            }
#pragma unroll
            for (int vt = 0; vt < 4; vt++)
#pragma unroll
                for (int rr = 0; rr < 4; rr++)
                    O[sub][vt][rr] *= sc[rr];
#pragma unroll
            for (int nt = 0; nt < 4; nt++)
#pragma unroll
                for (int rr = 0; rr < 4; rr++) {
                    int row = fq * 4 + rr;
                    int byte = ((row * 64 + nt * 16 + fr) * 2) ^ ((row & 7) << 4);
                    *(f16*)(Pb + byte) = (f16)ps[sub][nt][rr];
                }
            f16x8 pa[2];
#pragma unroll
            for (int ks = 0; ks < 2; ks++) {
                int byte = ((fr * 64 + ks * 32 + fq * 8) * 2) ^ ((fr & 7) << 4);
                pa[ks] = *(const f16x8*)(Pb + byte);
            }
#pragma unroll
            for (int vt = 0; vt < 4; vt++) {
                O[sub][vt] = mfma_f16(pa[0], vb[vt][0], O[sub][vt]);
                O[sub][vt] = mfma_f16(pa[1], vb[vt][1], O[sub][vt]);
            }
        }
    }
#pragma unroll
    for (int sub = 0; sub < 2; sub++) {
        float inv[4];
#pragma unroll
        for (int rr = 0; rr < 4; rr++) inv[rr] = 1.f / lsum[sub][rr];
#pragma unroll
        for (int vt = 0; vt < 4; vt++)
#pragma unroll
            for (int rr = 0; rr < 4; rr++) {
                float v = O[sub][vt][rr] * inv[rr];
                size_t idx = ((size_t)b * NSEQ + brow + sub * 16 + fq * 4 + rr) * DIM
                             + hd * 64 + vt * 16 + fr;
                attf[idx] = (f16)v;
            }
    }
}

// ---------------- BN apply (vectorized x4) ----------------
__global__ __launch_bounds__(256)
void bn_apply(float* __restrict__ h, f16* __restrict__ hf,
              const float* __restrict__ sums, const float* __restrict__ g,
              const float* __restrict__ bt, float* __restrict__ outp) {
    size_t i4 = (size_t)blockIdx.x * 256 + threadIdx.x;
    size_t idx = i4 * 4;
    int c = (int)(idx & (DIM - 1));
    float4 hv = *(float4*)&h[idx];
    float4 s4 = *(const float4*)&sums[c];
    float4 q4 = *(const float4*)&sums[DIM + c];
    float4 g4 = *(const float4*)&g[c];
    float4 b4 = *(const float4*)&bt[c];
    float o[4];
    const float invn = 1.f / BN_ROWS;
#pragma unroll
    for (int j = 0; j < 4; j++) {
        float mu = ((const float*)&s4)[j] * invn;
        float var = ((const float*)&q4)[j] * invn - mu * mu;
        o[j] = (((const float*)&hv)[j] - mu) * rsqrtf(var + 1e-5f)
               * ((const float*)&g4)[j] + ((const float*)&b4)[j];
    }
    *(float4*)&h[idx] = *(float4*)o;
    if (outp) *(float4*)&outp[idx] = *(float4*)o;
    f16x4 s;
#pragma unroll
    for (int j = 0; j < 4; j++) s[j] = (f16)o[j];
    *(f16x4*)&hf[idx] = s;
}

// ---------------- mean over n ----------------
__global__ __launch_bounds__(512)
void mean_kernel(const float* __restrict__ src, float* __restrict__ out2) {
    int b = blockIdx.x, seg = blockIdx.y, d = threadIdx.x;
    float acc = 0.f;
    for (int n = seg * 64; n < seg * 64 + 64; n++)
        acc += src[((size_t)b * NSEQ + n) * DIM + d];
    atomicAdd(&out2[b * DIM + d], acc * (1.f / NSEQ));
}

extern "C" void kernel_launch(void* const* d_in, const int* in_sizes, int n_in,
                              void* d_out, int out_size, void* d_ws, size_t ws_size,
                              hipStream_t stream) {
    const float* x   = (const float*)d_in[0];
    const int*   mask= (const int*)d_in[1];
    const float* We  = (const float*)d_in[2];
    const float* be  = (const float*)d_in[3];
    const float* Wq  = (const float*)d_in[4];
    const float* Wk  = (const float*)d_in[5];
    const float* Wv  = (const float*)d_in[6];
    const float* Wo  = (const float*)d_in[7];
    const float* g1  = (const float*)d_in[8];
    const float* bt1 = (const float*)d_in[9];
    const float* g2  = (const float*)d_in[10];
    const float* bt2 = (const float*)d_in[11];
    const float* W1  = (const float*)d_in[12];
    const float* bf1 = (const float*)d_in[13];
    const float* W2  = (const float*)d_in[14];
    const float* bf2 = (const float*)d_in[15];
    float* out = (float*)d_out;

    const size_t MiB = 1ull << 20;
    const size_t M1 = (size_t)BN_ROWS * DIM;
    char* base = (char*)d_ws;
    float* h     = (float*)base;                    // 0-32 MiB
    f16*   hf    = (f16*)(base + 32 * MiB);         // 16
    f16*   Qf    = (f16*)(base + 48 * MiB);         // 16
    f16*   Kf    = (f16*)(base + 64 * MiB);         // 16
    f16*   Vt    = (f16*)(base + 80 * MiB);         // 16
    f16*   attf  = (f16*)(base + 96 * MiB);         // 16
    f16*   ffh   = (f16*)(base + 48 * MiB);         // 64 MiB, reuses Qf..attf (dead by FFN)
    float* stats = (float*)(base + 112 * MiB);      // 4 KiB
    u64*   pmask = (u64*)(base + 112 * MiB + 65536);// 1 MiB
    f16*   wqkv  = (f16*)(base + 114 * MiB);        // 12.6 MiB
    f16*   wo    = wqkv + (size_t)4 * 1536 * 512;   // 2.1
    f16*   w1t   = wo   + (size_t)4 * 512 * 512;    // 8.4
    f16*   w2t   = w1t  + (size_t)4 * 2048 * 512;   // 8.4

    pack_qkv<<<dim3(4 * 1536 * 512 / 256), dim3(256), 0, stream>>>(Wq, Wk, Wv, wqkv);
    transpose_w<<<dim3(4 * 512 * 512 / 256), dim3(256), 0, stream>>>(Wo, wo, 512, 512);
    transpose_w<<<dim3(4 * 512 * 2048 / 256), dim3(256), 0, stream>>>(W1, w1t, 512, 2048);
    transpose_w<<<dim3(4 * 2048 * 512 / 256), dim3(256), 0, stream>>>(W2, w2t, 2048, 512);
    pack_mask<<<dim3(512), dim3(256), 0, stream>>>(mask, pmask);
    hipMemsetAsync(out + M1, 0, BATCH * DIM * sizeof(float), stream);

    embed_kernel<<<dim3(BN_ROWS), dim3(512), 0, stream>>>(x, We, be, h, hf);

    for (int l = 0; l < LAYERS; l++) {
        gemm_f16<2><<<dim3(1536 / 128, 128), dim3(256), 0, stream>>>(
            hf, wqkv + (size_t)l * 1536 * 512, nullptr, Qf, Kf, Vt,
            BN_ROWS, 1536, 512);

        attn_flash<<<dim3(1024), dim3(256), 0, stream>>>(Qf, Kf, Vt, pmask, attf);

        hipMemsetAsync(stats, 0, 1024 * sizeof(float), stream);
        gemm_f16<3><<<dim3(512 / 128, 128), dim3(256), 0, stream>>>(
            attf, wo + (size_t)l * 512 * 512, nullptr, h, stats, nullptr,
            BN_ROWS, 512, 512);
        bn_apply<<<dim3(M1 / 1024), dim3(256), 0, stream>>>(
            h, hf, stats, g1 + l * DIM, bt1 + l * DIM, nullptr);

        hipMemsetAsync(stats, 0, 1024 * sizeof(float), stream);
        gemm_f16<1><<<dim3(FF / 128, BN_ROWS / 128), dim3(256), 0, stream>>>(
            hf, w1t + (size_t)l * FF * DIM, bf1 + (size_t)l * FF,
            ffh, nullptr, nullptr, BN_ROWS, FF, DIM);
        gemm_f16<3><<<dim3(DIM / 128, BN_ROWS / 128), dim3(256), 0, stream>>>(
            ffh, w2t + (size_t)l * DIM * FF, bf2 + (size_t)l * DIM,
            h, stats, nullptr, BN_ROWS, DIM, FF);

        float* outp = (l == LAYERS - 1) ? out : nullptr;
        bn_apply<<<dim3(M1 / 1024), dim3(256), 0, stream>>>(
            h, hf, stats, g2 + l * DIM, bt2 + l * DIM, outp);
    }

    mean_kernel<<<dim3(BATCH, 8), dim3(512), 0, stream>>>(out, out + M1);
}